// Round 15
// baseline (142.931 us; speedup 1.0000x reference)
//
#include <hip/hip_runtime.h>

typedef unsigned int u32;
typedef unsigned long long u64;

#define B 8
#define H 1024
#define W 1024
#define TOPK 4096
#define GCAP 8192              // gathered per image
#define LBUFW 320              // per-wave slab size (empirical max ~165 + slack)
#define NSLAB 768              // waves per image (192 blocks x 4)
#define CSTR 32                // counter stride in u32 (128 B: no cross-image line bounce)
#define NB2 8192               // fine value buckets over [0.5,1)
#define HPAD 8200              // per-image hist/dp stride (u32)
#define BAND 4096              // gather band cap (actual band ~500 buckets)

__device__ __forceinline__ float max3(float a, float b, float c) {
    float r;
    asm("v_max3_f32 %0, %1, %2, %3" : "=v"(r) : "v"(a), "v"(b), "v"(c));
    return r;
}
#define MAX5R(A, j) max3(max3(A[j], A[(j)+1], A[(j)+2]), A[(j)+3], A[(j)+4])
#define OR5(A, j) (A[j] | A[(j)+1] | A[(j)+2] | A[(j)+3] | A[(j)+4])

__device__ __forceinline__ u32 bkt(u32 vb) {
    if (vb < 0x3F000000u) return 0u;
    u32 b = ((vb - 0x3F000000u) >> 10) + 1u;
    return b > NB2 ? NB2 : b;
}

__device__ __forceinline__ u64 xdilate(u64 m) {
    return m | (m << 1) | (m >> 1) | (m << 2) | (m >> 2);
}

__device__ __forceinline__ float xmax5(float v) {
    float u1 = __shfl_up(v, 1), d1 = __shfl_down(v, 1);
    float u2 = __shfl_up(v, 2), d2 = __shfl_down(v, 2);
    return max3(max3(v, u1, d1), u2, d2);
}

// mask-bit set -> 0 else v : single v_cndmask on the SGPR-pair ballot
__device__ __forceinline__ float selz(u64 m, float v) {
    float r;
    asm("v_cndmask_b32 %0, %1, 0, %2" : "=v"(r) : "v"(v), "s"(m));
    return r;
}
__device__ __forceinline__ float selnz(u64 m, float v) {
    float r;
    asm("v_cndmask_b32 %0, 0, %1, %2" : "=v"(r) : "v"(v), "s"(m));
    return r;
}

// ---------------- streaming register-pipeline NMS (r13 hot loop, slab flush) ----------------

__global__ __launch_bounds__(256, 4) void k_nms(const float* __restrict__ S_,
                                                u64* __restrict__ cand,
                                                u32* __restrict__ bcnt,
                                                u32* __restrict__ hist,
                                                u32* __restrict__ done) {
    __shared__ u64 lbuf[4][LBUFW];

    int lane = threadIdx.x & 63;
    int wslot = threadIdx.x >> 6;
    int sx = blockIdx.x * 4 + wslot;
    int sy = blockIdx.y;
    int img = blockIdx.z;
    int bid = blockIdx.x + 6 * blockIdx.y;          // 0..191

    // zero this block's disjoint slice of the fine histogram + done counter
    // (k_histscan only atomically adds / reads later -> no race, stream-ordered)
    {
        u32 base = (u32)bid * 43u;
        u32* gh = hist + (u32)img * HPAD;
        int t0 = threadIdx.x;
        if (t0 < 43 && base + t0 < HPAD) gh[base + t0] = 0;
        if (bid == 0 && t0 == 0) done[img * CSTR] = 0;
    }

    int gx0 = sx * 44 - 10;
    int gy0 = sy * 32;
    int gx = gx0 + lane;
    bool lxok = (unsigned)gx < (unsigned)W;
    u64 lanebit = 1ull << lane;
    const float* Sb = S_ + ((size_t)img << 20);

    u64 validx = __ballot(lxok);
    u64 emask = __ballot(lane >= 10 && lane <= 53 && gx >= 2 && gx <= W - 3);

    float S[14], R0[8], R1[8], R2[8], nxt[4];
    u64 M0[8], M1[8], SP1[6], SP2[6];
#pragma unroll
    for (int k = 0; k < 14; ++k) S[k] = -1.0f;
#pragma unroll
    for (int k = 0; k < 8; ++k) { R0[k] = -1e30f; R1[k] = -1e30f; R2[k] = -1e30f; M0[k] = 0; M1[k] = 0; }
#pragma unroll
    for (int k = 0; k < 6; ++k) { SP1[k] = 0; SP2[k] = 0; }

    u32 wbase = 0;
    int y0 = gy0 - 10;

#pragma unroll
    for (int j = 0; j < 4; ++j) {
        int gy = y0 + j;
        nxt[j] = ((unsigned)gy < (unsigned)H && lxok) ? Sb[(gy << 10) + gx] : -1.0f;
    }

    for (int cy = 0; cy < 13; ++cy, y0 += 4) {
#pragma unroll
        for (int j = 0; j < 4; ++j) S[10 + j] = nxt[j];
        if (cy < 12) {
#pragma unroll
            for (int j = 0; j < 4; ++j) {
                int gy = y0 + 4 + j;
                nxt[j] = ((unsigned)gy < (unsigned)H && lxok) ? Sb[(gy << 10) + gx] : -1.0f;
            }
        }
#pragma unroll
        for (int j = 0; j < 4; ++j) {
            R0[4 + j] = xmax5(S[10 + j]);
            float c0 = MAX5R(R0, j);
            u64 m0 = __ballot(S[j + 8] == c0) & validx;
            M0[4 + j] = m0;

            u64 sp1 = xdilate(OR5(M0, j));
            SP1[2 + j] = sp1;

            float ss1 = selz(sp1, S[j + 6]);
            R1[4 + j] = xmax5(ss1);
            float c1 = MAX5R(R1, j);
            float ss1b = selz(SP1[j], S[j + 4]);
            u64 new1 = __ballot(ss1b == c1) & validx;
            u64 m1 = M0[j] | (new1 & ~SP1[j]);
            M1[4 + j] = m1;

            u64 sp2 = xdilate(OR5(M1, j));
            SP2[2 + j] = sp2;

            float ss2 = selz(sp2, S[j + 2]);
            R2[4 + j] = xmax5(ss2);

            if (cy >= 5) {
                float c2 = MAX5R(R2, j);
                float ss2b = selz(SP2[j], S[j]);
                u64 new2 = __ballot(ss2b == c2) & validx;
                u64 m2 = M1[j] | (new2 & ~SP2[j]);
                int gy_out = y0 + j - 10;
                if (gy_out >= 2 && gy_out <= H - 3) {
                    float val = selnz(m2, S[j]);
                    u64 bm = __ballot(val > 0.0f) & emask;
                    if (bm) {
                        u32 cw = (u32)__popcll(bm);
                        u32 prefix = (u32)__popcll(bm & (lanebit - 1ull));
                        if ((bm & lanebit) && (wbase + prefix) < LBUFW) {
                            u64 key = (((u64)__float_as_uint(val)) << 32) |
                                      (u32)(~(u32)((gy_out << 10) + gx));
                            lbuf[wslot][wbase + prefix] = key;
                        }
                        wbase += cw;
                    }
                }
            }
        }
#pragma unroll
        for (int k = 0; k < 10; ++k) S[k] = S[k + 4];
#pragma unroll
        for (int k = 0; k < 4; ++k) {
            R0[k] = R0[k + 4]; R1[k] = R1[k + 4]; R2[k] = R2[k + 4];
            M0[k] = M0[k + 4]; M1[k] = M1[k + 4];
        }
#pragma unroll
        for (int k = 0; k < 2; ++k) { SP1[k] = SP1[k + 4]; SP2[k] = SP2[k + 4]; }
    }

    // slab flush: fixed per-wave slot, no global atomics
    u32 total = wbase > LBUFW ? LBUFW : wbase;
    int slab = bid * 4 + wslot;                     // 0..767
    u64* dst = cand + ((size_t)img << 18) + (size_t)slab * LBUFW;
    for (u32 i = lane; i < total; i += 64)
        dst[i] = lbuf[wslot][i];
    if (lane == 0) bcnt[img * NSLAB + slab] = total;
}

// ---- fused: fine histogram (16 blocks/img) + last-block descending scan ----

__global__ __launch_bounds__(256) void k_histscan(const u64* __restrict__ cand,
                                                  const u32* __restrict__ bcnt,
                                                  u32* __restrict__ hist,
                                                  u32* __restrict__ done,
                                                  u32* __restrict__ dparr,
                                                  u32* __restrict__ dpcnt,
                                                  u32* __restrict__ Bsr,
                                                  u32* __restrict__ gtot) {
    __shared__ u32 h[NB2 + 1];          // 32.8 KB
    __shared__ u32 wpart[4], woff[4];
    __shared__ u32 sflag, sBs, sGc, sH0;
    int img = blockIdx.y;
    int t = threadIdx.x;

    for (int i = t; i <= NB2; i += 256) h[i] = 0;
    __syncthreads();

    const u64* c = cand + ((size_t)img << 18);
    for (int s = 0; s < NSLAB / 16; ++s) {
        int slab = blockIdx.x * (NSLAB / 16) + s;
        u32 n = bcnt[img * NSLAB + slab];
        if (n > LBUFW) n = LBUFW;
        const u64* cs = c + (size_t)slab * LBUFW;
        for (u32 i = t; i < n; i += 256)
            atomicAdd(&h[bkt((u32)(cs[i] >> 32))], 1u);
    }
    __syncthreads();

    u32* gh = hist + (u32)img * HPAD;
    for (int i = t; i <= NB2; i += 256) {
        u32 v = h[i];
        if (v) atomicAdd(&gh[i], v);
    }
    __threadfence();                    // release: our hist adds visible
    __syncthreads();
    if (t == 0) {
        u32 prev = atomicAdd(&done[img * CSTR], 1u);
        sflag = (prev == 15) ? 1u : 0u;
        sBs = 0; sGc = 0;
    }
    __syncthreads();
    if (!sflag) return;
    __threadfence();                    // acquire side

    // last block for this image: descending scan over global hist
    int lane = t & 63, wid = t >> 6;
    int hi = NB2 - 32 * t;              // owns buckets hi..hi-31 (covers 8192..1)
    u32 loc[32];
    u32 psum = 0;
#pragma unroll
    for (int i = 0; i < 32; ++i) {
        loc[i] = __hip_atomic_load(&gh[hi - i], __ATOMIC_RELAXED, __HIP_MEMORY_SCOPE_AGENT);
        psum += loc[i];
    }
    if (t == 255)
        sH0 = __hip_atomic_load(&gh[0], __ATOMIC_RELAXED, __HIP_MEMORY_SCOPE_AGENT);
    u32 incl = psum;
#pragma unroll
    for (int d = 1; d < 64; d <<= 1) {
        u32 x = (u32)__shfl_up((int)incl, d);
        if (lane >= d) incl += x;
    }
    if (lane == 63) wpart[wid] = incl;
    __syncthreads();
    if (t == 0) { u32 a = 0; for (int w2 = 0; w2 < 4; ++w2) { woff[w2] = a; a += wpart[w2]; } }
    __syncthreads();
    u32 total1 = woff[3] + wpart[3];
    u32 excl = incl - psum + woff[wid];     // keys in buckets > hi

    u32* dpi = dparr + (u32)img * HPAD;
    u32* dci = dpcnt + (u32)img * HPAD;
    u32 dpv = excl;
#pragma unroll
    for (int i = 0; i < 32; ++i) {
        dpi[hi - i] = dpv;
        dci[hi - i] = dpv;
        dpv += loc[i];
    }
    if (t == 255) { dpi[0] = dpv; dci[0] = dpv; }   // dpv == total1
    if (excl < TOPK && excl + psum >= TOPK) {
        u32 cum = excl;
#pragma unroll
        for (int i = 0; i < 32; ++i) {
            cum += loc[i];
            if (cum >= TOPK) { sBs = (u32)(hi - i); sGc = cum; break; }
        }
    }
    __syncthreads();
    if (t == 0) {
        u32 bs = sBs, gc = sGc;
        if (total1 < TOPK) { bs = 0; gc = total1 + sH0; }
        Bsr[img * CSTR] = bs;
        gtot[img * CSTR] = gc > GCAP ? GCAP : gc;
    }
}

// ---- gather with two-level counting-sort scatter -> bucket-segmented gath ----

__global__ __launch_bounds__(256) void k_gather(const u64* __restrict__ cand,
                                                const u32* __restrict__ bcnt,
                                                const u32* __restrict__ Bsr,
                                                u32* __restrict__ dpcnt,
                                                u64* __restrict__ gath) {
    __shared__ u32 hb[BAND];   // counts, then consumed offsets
    __shared__ u32 ho[BAND];   // global bases
    int img = blockIdx.y, t = threadIdx.x;
    for (int i = t; i < BAND; i += 256) hb[i] = 0;
    __syncthreads();
    u32 Bs = Bsr[img * CSTR];
    const u64* c = cand + ((size_t)img << 18);
    u32* dci = dpcnt + (u32)img * HPAD;

    for (int s = 0; s < NSLAB / 16; ++s) {
        int slab = blockIdx.x * (NSLAB / 16) + s;
        u32 n = bcnt[img * NSLAB + slab];
        if (n > LBUFW) n = LBUFW;
        const u64* cs = c + (size_t)slab * LBUFW;
        for (u32 i = t; i < n; i += 256) {
            u32 b = bkt((u32)(cs[i] >> 32));
            if (b >= Bs) {
                u32 idx = b - Bs;
                if (idx < BAND) atomicAdd(&hb[idx], 1u);
            }
        }
    }
    __syncthreads();
    for (int i = t; i < BAND; i += 256) {
        u32 cv = hb[i];
        if (cv) { ho[i] = atomicAdd(&dci[Bs + i], cv); hb[i] = 0; }
    }
    __syncthreads();
    u64* g = gath + ((size_t)img << 13);
    for (int s = 0; s < NSLAB / 16; ++s) {
        int slab = blockIdx.x * (NSLAB / 16) + s;
        u32 n = bcnt[img * NSLAB + slab];
        if (n > LBUFW) n = LBUFW;
        const u64* cs = c + (size_t)slab * LBUFW;
        for (u32 i = t; i < n; i += 256) {
            u64 key = cs[i];
            u32 b = bkt((u32)(key >> 32));
            if (b < Bs) continue;
            u32 idx = b - Bs;
            u32 pos;
            if (idx < BAND) pos = ho[idx] + atomicAdd(&hb[idx], 1u);
            else pos = atomicAdd(&dci[b], 1u);     // never on this data
            if (pos < GCAP) g[pos] = key;
        }
    }
}

// ---- fused: exact rank (bucket-segment scan) + softmax patch + dispersity + bilinear ----

__global__ __launch_bounds__(256) void k_rankfinal(const u64* __restrict__ gath,
                                                   const u32* __restrict__ gtot,
                                                   const u32* __restrict__ dparr,
                                                   const float* __restrict__ S,
                                                   float* __restrict__ out) {
    int img = blockIdx.y;
    u32 n = gtot[img * CSTR];
    if (n > GCAP) n = GCAP;
    u32 i = blockIdx.x * 256 + threadIdx.x;
    if (i >= n) return;
    const u64* g = gath + ((size_t)img << 13);
    u64 key = g[i];
    u32 b = bkt((u32)(key >> 32));
    const u32* dpi = dparr + (u32)img * HPAD;
    u32 lo = dpi[b];
    u32 hiE = (b >= 1) ? dpi[b - 1] : n;
    if (hiE > n) hiE = n;
    u32 r = lo;
    for (u32 j = lo; j < hiE; ++j) r += (g[j] > key);
    if (r >= TOPK) return;

    u32 rem = ~(u32)(key & 0xFFFFFFFFull);
    int row = (int)(rem >> 10);
    int col = (int)(rem & (W - 1));
    const float* Sb = S + ((size_t)img << 20);

    float p[25];
    float mx = -1e30f;
#pragma unroll
    for (int a2 = 0; a2 < 5; ++a2) {
        int y = row + a2 - 2;
#pragma unroll
        for (int c2 = 0; c2 < 5; ++c2) {
            int x = col + c2 - 2;
            float v = (y >= 0 && y < H && x >= 0 && x < W) ? Sb[(y << 10) + x] : 0.0f;
            p[a2 * 5 + c2] = v;
            mx = fmaxf(mx, v);
        }
    }
    float sum = 0.0f, sx = 0.0f, sy = 0.0f;
#pragma unroll
    for (int a2 = 0; a2 < 5; ++a2) {
#pragma unroll
        for (int c2 = 0; c2 < 5; ++c2) {
            float e = expf((p[a2 * 5 + c2] - mx) / 0.1f);
            p[a2 * 5 + c2] = e;
            sum += e;
            sx += e * (float)(c2 - 2);
            sy += e * (float)(a2 - 2);
        }
    }
    float rx = sx / sum, ry = sy / sum;
    float sd = 0.0f;
#pragma unroll
    for (int a2 = 0; a2 < 5; ++a2) {
#pragma unroll
        for (int c2 = 0; c2 < 5; ++c2) {
            float dxx = ((float)(c2 - 2) - rx) * 0.5f;
            float dyy = ((float)(a2 - 2) - ry) * 0.5f;
            sd += p[a2 * 5 + c2] * (dxx * dxx + dyy * dyy);
        }
    }
    float disp = sd / sum;
    float kx = ((float)col + rx) / (float)(W - 1) * 2.0f - 1.0f;
    float ky = ((float)row + ry) / (float)(H - 1) * 2.0f - 1.0f;

    float px = (kx + 1.0f) * 0.5f * (float)(W - 1);
    float py = (ky + 1.0f) * 0.5f * (float)(H - 1);
    float x0 = floorf(px), y0 = floorf(py);
    float wx1 = px - x0, wx0 = 1.0f - wx1;
    float wy1 = py - y0, wy0 = 1.0f - wy1;

    float gg[4];
    float xs[4] = {x0, x0 + 1.0f, x0, x0 + 1.0f};
    float ys[4] = {y0, y0, y0 + 1.0f, y0 + 1.0f};
#pragma unroll
    for (int q = 0; q < 4; ++q) {
        int xi = (int)xs[q]; xi = xi < 0 ? 0 : (xi > W - 1 ? W - 1 : xi);
        int yi = (int)ys[q]; yi = yi < 0 ? 0 : (yi > H - 1 ? H - 1 : yi);
        bool valid = (xs[q] >= 0.0f) && (xs[q] <= (float)(W - 1)) &&
                     (ys[q] >= 0.0f) && (ys[q] <= (float)(H - 1));
        gg[q] = valid ? Sb[(yi << 10) + xi] : 0.0f;
    }
    float score = wy0 * wx0 * gg[0] + wy0 * wx1 * gg[1] + wy1 * wx0 * gg[2] + wy1 * wx1 * gg[3];

    u32 slot = ((u32)img << 12) + r;
    out[(size_t)slot * 2]     = kx;
    out[(size_t)slot * 2 + 1] = ky;
    out[B * TOPK * 2 + slot]            = disp;
    out[B * TOPK * 2 + B * TOPK + slot] = score;
}

// ---------------- launch ----------------

extern "C" void kernel_launch(void* const* d_in, const int* in_sizes, int n_in,
                              void* d_out, int out_size, void* d_ws, size_t ws_size,
                              hipStream_t stream) {
    const float* S = (const float*)d_in[0];
    float* out = (float*)d_out;

    char* w = (char*)d_ws;
    u64* cand = (u64*)w;        w += (size_t)B * (1 << 18) * 8;   // slabbed: 768 x 320 per image
    u64* gath = (u64*)w;        w += (size_t)B * GCAP * 8;
    u32* hist = (u32*)w;        w += (size_t)B * HPAD * 4;
    u32* dparr = (u32*)w;       w += (size_t)B * HPAD * 4;
    u32* dpcnt = (u32*)w;       w += (size_t)B * HPAD * 4;
    u32* bcnt = (u32*)w;        w += (size_t)B * NSLAB * 4;
    u32* done = (u32*)w;        w += B * CSTR * 4;
    u32* Bsr = (u32*)w;         w += B * CSTR * 4;
    u32* gtot = (u32*)w;        w += B * CSTR * 4;

    // no memset: hist+done zeroed inside k_nms; bcnt fully written by k_nms;
    // dparr/dpcnt/Bsr/gtot fully written by k_histscan; gath[0..gtot) by k_gather.

    k_nms<<<dim3(6, 32, B), 256, 0, stream>>>(S, cand, bcnt, hist, done);
    k_histscan<<<dim3(16, B), 256, 0, stream>>>(cand, bcnt, hist, done, dparr, dpcnt, Bsr, gtot);
    k_gather<<<dim3(16, B), 256, 0, stream>>>(cand, bcnt, Bsr, dpcnt, gath);
    k_rankfinal<<<dim3(32, B), 256, 0, stream>>>(gath, gtot, dparr, S, out);
}

// Round 16
// 142.140 us; speedup vs baseline: 1.0056x; 1.0056x over previous
//
#include <hip/hip_runtime.h>

typedef unsigned int u32;
typedef unsigned long long u64;

#define B 8
#define H 1024
#define W 1024
#define TOPK 4096
#define GCAP 8192              // gathered per image
#define LBUFW 320              // per-wave slab size (empirical max ~165 + slack)
#define NSLAB 768              // waves per image (192 blocks x 4)
#define CSTR 32                // counter stride in u32 (128 B: no cross-image line bounce)
#define NB2 8192               // fine value buckets over [0.5,1)
#define HPAD 8200              // per-image hist/dp stride (u32)
#define BAND 4096              // gather band cap (actual band ~500 buckets)

__device__ __forceinline__ float max3(float a, float b, float c) {
    float r;
    asm("v_max3_f32 %0, %1, %2, %3" : "=v"(r) : "v"(a), "v"(b), "v"(c));
    return r;
}
#define MAX5R(A, j) max3(max3(A[j], A[(j)+1], A[(j)+2]), A[(j)+3], A[(j)+4])
#define OR5(A, j) (A[j] | A[(j)+1] | A[(j)+2] | A[(j)+3] | A[(j)+4])

__device__ __forceinline__ u32 bkt(u32 vb) {
    if (vb < 0x3F000000u) return 0u;
    u32 b = ((vb - 0x3F000000u) >> 10) + 1u;
    return b > NB2 ? NB2 : b;
}

__device__ __forceinline__ u64 xdilate(u64 m) {
    return m | (m << 1) | (m >> 1) | (m << 2) | (m >> 2);
}

__device__ __forceinline__ float xmax5(float v) {
    float u1 = __shfl_up(v, 1), d1 = __shfl_down(v, 1);
    float u2 = __shfl_up(v, 2), d2 = __shfl_down(v, 2);
    return max3(max3(v, u1, d1), u2, d2);
}

// mask-bit set -> 0 else v : single v_cndmask on the SGPR-pair ballot
__device__ __forceinline__ float selz(u64 m, float v) {
    float r;
    asm("v_cndmask_b32 %0, %1, 0, %2" : "=v"(r) : "v"(v), "s"(m));
    return r;
}
__device__ __forceinline__ float selnz(u64 m, float v) {
    float r;
    asm("v_cndmask_b32 %0, 0, %1, %2" : "=v"(r) : "v"(v), "s"(m));
    return r;
}

// ---------------- streaming register-pipeline NMS (r13 hot loop, slab flush) ----------------

__global__ __launch_bounds__(256, 4) void k_nms(const float* __restrict__ S_,
                                                u64* __restrict__ cand,
                                                u32* __restrict__ bcnt,
                                                u32* __restrict__ hist,
                                                u32* __restrict__ done) {
    __shared__ u64 lbuf[4][LBUFW];

    int lane = threadIdx.x & 63;
    int wslot = threadIdx.x >> 6;
    int sx = blockIdx.x * 4 + wslot;
    int sy = blockIdx.y;
    int img = blockIdx.z;
    int bid = blockIdx.x + 6 * blockIdx.y;          // 0..191

    // zero this block's disjoint slice of the fine histogram + done counter
    // (k_histscan only atomically adds / reads later -> no race, stream-ordered)
    {
        u32 base = (u32)bid * 43u;
        u32* gh = hist + (u32)img * HPAD;
        int t0 = threadIdx.x;
        if (t0 < 43 && base + t0 < HPAD) gh[base + t0] = 0;
        if (bid == 0 && t0 == 0) done[img * CSTR] = 0;
    }

    int gx0 = sx * 44 - 10;
    int gy0 = sy * 32;
    int gx = gx0 + lane;
    bool lxok = (unsigned)gx < (unsigned)W;
    u64 lanebit = 1ull << lane;
    const float* Sb = S_ + ((size_t)img << 20);

    u64 validx = __ballot(lxok);
    u64 emask = __ballot(lane >= 10 && lane <= 53 && gx >= 2 && gx <= W - 3);

    float S[14], R0[8], R1[8], R2[8], nxt[4];
    u64 M0[8], M1[8], SP1[6], SP2[6];
#pragma unroll
    for (int k = 0; k < 14; ++k) S[k] = -1.0f;
#pragma unroll
    for (int k = 0; k < 8; ++k) { R0[k] = -1e30f; R1[k] = -1e30f; R2[k] = -1e30f; M0[k] = 0; M1[k] = 0; }
#pragma unroll
    for (int k = 0; k < 6; ++k) { SP1[k] = 0; SP2[k] = 0; }

    u32 wbase = 0;
    int y0 = gy0 - 10;

#pragma unroll
    for (int j = 0; j < 4; ++j) {
        int gy = y0 + j;
        nxt[j] = ((unsigned)gy < (unsigned)H && lxok) ? Sb[(gy << 10) + gx] : -1.0f;
    }

    for (int cy = 0; cy < 13; ++cy, y0 += 4) {
#pragma unroll
        for (int j = 0; j < 4; ++j) S[10 + j] = nxt[j];
        if (cy < 12) {
#pragma unroll
            for (int j = 0; j < 4; ++j) {
                int gy = y0 + 4 + j;
                nxt[j] = ((unsigned)gy < (unsigned)H && lxok) ? Sb[(gy << 10) + gx] : -1.0f;
            }
        }
#pragma unroll
        for (int j = 0; j < 4; ++j) {
            R0[4 + j] = xmax5(S[10 + j]);
            float c0 = MAX5R(R0, j);
            u64 m0 = __ballot(S[j + 8] == c0) & validx;
            M0[4 + j] = m0;

            u64 sp1 = xdilate(OR5(M0, j));
            SP1[2 + j] = sp1;

            float ss1 = selz(sp1, S[j + 6]);
            R1[4 + j] = xmax5(ss1);
            float c1 = MAX5R(R1, j);
            float ss1b = selz(SP1[j], S[j + 4]);
            u64 new1 = __ballot(ss1b == c1) & validx;
            u64 m1 = M0[j] | (new1 & ~SP1[j]);
            M1[4 + j] = m1;

            u64 sp2 = xdilate(OR5(M1, j));
            SP2[2 + j] = sp2;

            float ss2 = selz(sp2, S[j + 2]);
            R2[4 + j] = xmax5(ss2);

            if (cy >= 5) {
                float c2 = MAX5R(R2, j);
                float ss2b = selz(SP2[j], S[j]);
                u64 new2 = __ballot(ss2b == c2) & validx;
                u64 m2 = M1[j] | (new2 & ~SP2[j]);
                int gy_out = y0 + j - 10;
                if (gy_out >= 2 && gy_out <= H - 3) {
                    float val = selnz(m2, S[j]);
                    u64 bm = __ballot(val > 0.0f) & emask;
                    if (bm) {
                        u32 cw = (u32)__popcll(bm);
                        u32 prefix = (u32)__popcll(bm & (lanebit - 1ull));
                        if ((bm & lanebit) && (wbase + prefix) < LBUFW) {
                            u64 key = (((u64)__float_as_uint(val)) << 32) |
                                      (u32)(~(u32)((gy_out << 10) + gx));
                            lbuf[wslot][wbase + prefix] = key;
                        }
                        wbase += cw;
                    }
                }
            }
        }
#pragma unroll
        for (int k = 0; k < 10; ++k) S[k] = S[k + 4];
#pragma unroll
        for (int k = 0; k < 4; ++k) {
            R0[k] = R0[k + 4]; R1[k] = R1[k + 4]; R2[k] = R2[k + 4];
            M0[k] = M0[k + 4]; M1[k] = M1[k + 4];
        }
#pragma unroll
        for (int k = 0; k < 2; ++k) { SP1[k] = SP1[k + 4]; SP2[k] = SP2[k + 4]; }
    }

    // slab flush: fixed per-wave slot, no global atomics
    u32 total = wbase > LBUFW ? LBUFW : wbase;
    int slab = bid * 4 + wslot;                     // 0..767
    u64* dst = cand + ((size_t)img << 18) + (size_t)slab * LBUFW;
    for (u32 i = lane; i < total; i += 64)
        dst[i] = lbuf[wslot][i];
    if (lane == 0) bcnt[img * NSLAB + slab] = total;
}

// ---- fused: fine histogram (16 blocks/img) + last-block descending scan ----

__global__ __launch_bounds__(256) void k_histscan(const u64* __restrict__ cand,
                                                  const u32* __restrict__ bcnt,
                                                  u32* __restrict__ hist,
                                                  u32* __restrict__ done,
                                                  u32* __restrict__ dparr,
                                                  u32* __restrict__ dpcnt,
                                                  u32* __restrict__ Bsr,
                                                  u32* __restrict__ gtot) {
    __shared__ u32 h[NB2 + 1];          // 32.8 KB
    __shared__ u32 wpart[4], woff[4];
    __shared__ u32 sflag, sBs, sGc, sH0;
    int img = blockIdx.y;
    int t = threadIdx.x;

    for (int i = t; i <= NB2; i += 256) h[i] = 0;
    __syncthreads();

    const u64* c = cand + ((size_t)img << 18);
    for (int s = 0; s < NSLAB / 16; ++s) {
        int slab = blockIdx.x * (NSLAB / 16) + s;
        u32 n = bcnt[img * NSLAB + slab];
        if (n > LBUFW) n = LBUFW;
        const u64* cs = c + (size_t)slab * LBUFW;
        for (u32 i = t; i < n; i += 256)
            atomicAdd(&h[bkt((u32)(cs[i] >> 32))], 1u);
    }
    __syncthreads();

    u32* gh = hist + (u32)img * HPAD;
    for (int i = t; i <= NB2; i += 256) {
        u32 v = h[i];
        if (v) atomicAdd(&gh[i], v);
    }
    __threadfence();                    // release: our hist adds visible
    __syncthreads();
    if (t == 0) {
        u32 prev = atomicAdd(&done[img * CSTR], 1u);
        sflag = (prev == 15) ? 1u : 0u;
        sBs = 0; sGc = 0;
    }
    __syncthreads();
    if (!sflag) return;
    __threadfence();                    // acquire side

    // last block for this image: descending scan over global hist
    int lane = t & 63, wid = t >> 6;
    int hi = NB2 - 32 * t;              // owns buckets hi..hi-31 (covers 8192..1)
    u32 loc[32];
    u32 psum = 0;
#pragma unroll
    for (int i = 0; i < 32; ++i) {
        loc[i] = __hip_atomic_load(&gh[hi - i], __ATOMIC_RELAXED, __HIP_MEMORY_SCOPE_AGENT);
        psum += loc[i];
    }
    if (t == 255)
        sH0 = __hip_atomic_load(&gh[0], __ATOMIC_RELAXED, __HIP_MEMORY_SCOPE_AGENT);
    u32 incl = psum;
#pragma unroll
    for (int d = 1; d < 64; d <<= 1) {
        u32 x = (u32)__shfl_up((int)incl, d);
        if (lane >= d) incl += x;
    }
    if (lane == 63) wpart[wid] = incl;
    __syncthreads();
    if (t == 0) { u32 a = 0; for (int w2 = 0; w2 < 4; ++w2) { woff[w2] = a; a += wpart[w2]; } }
    __syncthreads();
    u32 total1 = woff[3] + wpart[3];
    u32 excl = incl - psum + woff[wid];     // keys in buckets > hi

    u32* dpi = dparr + (u32)img * HPAD;
    u32* dci = dpcnt + (u32)img * HPAD;
    u32 dpv = excl;
#pragma unroll
    for (int i = 0; i < 32; ++i) {
        dpi[hi - i] = dpv;
        dci[hi - i] = dpv;
        dpv += loc[i];
    }
    if (t == 255) { dpi[0] = dpv; dci[0] = dpv; }   // dpv == total1
    if (excl < TOPK && excl + psum >= TOPK) {
        u32 cum = excl;
#pragma unroll
        for (int i = 0; i < 32; ++i) {
            cum += loc[i];
            if (cum >= TOPK) { sBs = (u32)(hi - i); sGc = cum; break; }
        }
    }
    __syncthreads();
    if (t == 0) {
        u32 bs = sBs, gc = sGc;
        if (total1 < TOPK) { bs = 0; gc = total1 + sH0; }
        Bsr[img * CSTR] = bs;
        gtot[img * CSTR] = gc > GCAP ? GCAP : gc;
    }
}

// ---- gather with two-level counting-sort scatter -> bucket-segmented gath ----

__global__ __launch_bounds__(256) void k_gather(const u64* __restrict__ cand,
                                                const u32* __restrict__ bcnt,
                                                const u32* __restrict__ Bsr,
                                                u32* __restrict__ dpcnt,
                                                u64* __restrict__ gath) {
    __shared__ u32 hb[BAND];   // counts, then consumed offsets
    __shared__ u32 ho[BAND];   // global bases
    int img = blockIdx.y, t = threadIdx.x;
    for (int i = t; i < BAND; i += 256) hb[i] = 0;
    __syncthreads();
    u32 Bs = Bsr[img * CSTR];
    const u64* c = cand + ((size_t)img << 18);
    u32* dci = dpcnt + (u32)img * HPAD;

    for (int s = 0; s < NSLAB / 16; ++s) {
        int slab = blockIdx.x * (NSLAB / 16) + s;
        u32 n = bcnt[img * NSLAB + slab];
        if (n > LBUFW) n = LBUFW;
        const u64* cs = c + (size_t)slab * LBUFW;
        for (u32 i = t; i < n; i += 256) {
            u32 b = bkt((u32)(cs[i] >> 32));
            if (b >= Bs) {
                u32 idx = b - Bs;
                if (idx < BAND) atomicAdd(&hb[idx], 1u);
            }
        }
    }
    __syncthreads();
    for (int i = t; i < BAND; i += 256) {
        u32 cv = hb[i];
        if (cv) { ho[i] = atomicAdd(&dci[Bs + i], cv); hb[i] = 0; }
    }
    __syncthreads();
    u64* g = gath + ((size_t)img << 13);
    for (int s = 0; s < NSLAB / 16; ++s) {
        int slab = blockIdx.x * (NSLAB / 16) + s;
        u32 n = bcnt[img * NSLAB + slab];
        if (n > LBUFW) n = LBUFW;
        const u64* cs = c + (size_t)slab * LBUFW;
        for (u32 i = t; i < n; i += 256) {
            u64 key = cs[i];
            u32 b = bkt((u32)(key >> 32));
            if (b < Bs) continue;
            u32 idx = b - Bs;
            u32 pos;
            if (idx < BAND) pos = ho[idx] + atomicAdd(&hb[idx], 1u);
            else pos = atomicAdd(&dci[b], 1u);     // never on this data
            if (pos < GCAP) g[pos] = key;
        }
    }
}

// ---- fused: exact rank (bucket-segment scan) + softmax patch + dispersity + bilinear ----

__global__ __launch_bounds__(256) void k_rankfinal(const u64* __restrict__ gath,
                                                   const u32* __restrict__ gtot,
                                                   const u32* __restrict__ dparr,
                                                   const float* __restrict__ S,
                                                   float* __restrict__ out) {
    int img = blockIdx.y;
    u32 n = gtot[img * CSTR];
    if (n > GCAP) n = GCAP;
    u32 i = blockIdx.x * 256 + threadIdx.x;
    if (i >= n) return;
    const u64* g = gath + ((size_t)img << 13);
    u64 key = g[i];
    u32 b = bkt((u32)(key >> 32));
    const u32* dpi = dparr + (u32)img * HPAD;
    u32 lo = dpi[b];
    u32 hiE = (b >= 1) ? dpi[b - 1] : n;
    if (hiE > n) hiE = n;
    u32 r = lo;
    for (u32 j = lo; j < hiE; ++j) r += (g[j] > key);
    if (r >= TOPK) return;

    u32 rem = ~(u32)(key & 0xFFFFFFFFull);
    int row = (int)(rem >> 10);
    int col = (int)(rem & (W - 1));
    const float* Sb = S + ((size_t)img << 20);

    float p[25];
    float mx = -1e30f;
#pragma unroll
    for (int a2 = 0; a2 < 5; ++a2) {
        int y = row + a2 - 2;
#pragma unroll
        for (int c2 = 0; c2 < 5; ++c2) {
            int x = col + c2 - 2;
            float v = (y >= 0 && y < H && x >= 0 && x < W) ? Sb[(y << 10) + x] : 0.0f;
            p[a2 * 5 + c2] = v;
            mx = fmaxf(mx, v);
        }
    }
    float sum = 0.0f, sx = 0.0f, sy = 0.0f;
#pragma unroll
    for (int a2 = 0; a2 < 5; ++a2) {
#pragma unroll
        for (int c2 = 0; c2 < 5; ++c2) {
            float e = expf((p[a2 * 5 + c2] - mx) / 0.1f);
            p[a2 * 5 + c2] = e;
            sum += e;
            sx += e * (float)(c2 - 2);
            sy += e * (float)(a2 - 2);
        }
    }
    float rx = sx / sum, ry = sy / sum;
    float sd = 0.0f;
#pragma unroll
    for (int a2 = 0; a2 < 5; ++a2) {
#pragma unroll
        for (int c2 = 0; c2 < 5; ++c2) {
            float dxx = ((float)(c2 - 2) - rx) * 0.5f;
            float dyy = ((float)(a2 - 2) - ry) * 0.5f;
            sd += p[a2 * 5 + c2] * (dxx * dxx + dyy * dyy);
        }
    }
    float disp = sd / sum;
    float kx = ((float)col + rx) / (float)(W - 1) * 2.0f - 1.0f;
    float ky = ((float)row + ry) / (float)(H - 1) * 2.0f - 1.0f;

    float px = (kx + 1.0f) * 0.5f * (float)(W - 1);
    float py = (ky + 1.0f) * 0.5f * (float)(H - 1);
    float x0 = floorf(px), y0 = floorf(py);
    float wx1 = px - x0, wx0 = 1.0f - wx1;
    float wy1 = py - y0, wy0 = 1.0f - wy1;

    float gg[4];
    float xs[4] = {x0, x0 + 1.0f, x0, x0 + 1.0f};
    float ys[4] = {y0, y0, y0 + 1.0f, y0 + 1.0f};
#pragma unroll
    for (int q = 0; q < 4; ++q) {
        int xi = (int)xs[q]; xi = xi < 0 ? 0 : (xi > W - 1 ? W - 1 : xi);
        int yi = (int)ys[q]; yi = yi < 0 ? 0 : (yi > H - 1 ? H - 1 : yi);
        bool valid = (xs[q] >= 0.0f) && (xs[q] <= (float)(W - 1)) &&
                     (ys[q] >= 0.0f) && (ys[q] <= (float)(H - 1));
        gg[q] = valid ? Sb[(yi << 10) + xi] : 0.0f;
    }
    float score = wy0 * wx0 * gg[0] + wy0 * wx1 * gg[1] + wy1 * wx0 * gg[2] + wy1 * wx1 * gg[3];

    u32 slot = ((u32)img << 12) + r;
    out[(size_t)slot * 2]     = kx;
    out[(size_t)slot * 2 + 1] = ky;
    out[B * TOPK * 2 + slot]            = disp;
    out[B * TOPK * 2 + B * TOPK + slot] = score;
}

// ---------------- launch ----------------

extern "C" void kernel_launch(void* const* d_in, const int* in_sizes, int n_in,
                              void* d_out, int out_size, void* d_ws, size_t ws_size,
                              hipStream_t stream) {
    const float* S = (const float*)d_in[0];
    float* out = (float*)d_out;

    char* w = (char*)d_ws;
    u64* cand = (u64*)w;        w += (size_t)B * (1 << 18) * 8;   // slabbed: 768 x 320 per image
    u64* gath = (u64*)w;        w += (size_t)B * GCAP * 8;
    u32* hist = (u32*)w;        w += (size_t)B * HPAD * 4;
    u32* dparr = (u32*)w;       w += (size_t)B * HPAD * 4;
    u32* dpcnt = (u32*)w;       w += (size_t)B * HPAD * 4;
    u32* bcnt = (u32*)w;        w += (size_t)B * NSLAB * 4;
    u32* done = (u32*)w;        w += B * CSTR * 4;
    u32* Bsr = (u32*)w;         w += B * CSTR * 4;
    u32* gtot = (u32*)w;        w += B * CSTR * 4;

    // no memset: hist+done zeroed inside k_nms; bcnt fully written by k_nms;
    // dparr/dpcnt/Bsr/gtot fully written by k_histscan; gath[0..gtot) by k_gather.

    k_nms<<<dim3(6, 32, B), 256, 0, stream>>>(S, cand, bcnt, hist, done);
    k_histscan<<<dim3(16, B), 256, 0, stream>>>(cand, bcnt, hist, done, dparr, dpcnt, Bsr, gtot);
    k_gather<<<dim3(16, B), 256, 0, stream>>>(cand, bcnt, Bsr, dpcnt, gath);
    k_rankfinal<<<dim3(32, B), 256, 0, stream>>>(gath, gtot, dparr, S, out);
}

// Round 17
// 107.282 us; speedup vs baseline: 1.3323x; 1.3249x over previous
//
#include <hip/hip_runtime.h>

typedef unsigned int u32;
typedef unsigned long long u64;

#define B 8
#define H 1024
#define W 1024
#define TOPK 4096
#define GCAP 8192              // gathered per image
#define LBUFW 320              // per-wave slab size (empirical max ~165 + slack)
#define NSLAB 768              // waves per image (192 blocks x 4)
#define SPW 12                 // slabs per consumer wave (64 waves x 12 = 768)
#define CSTR 32                // counter stride in u32 (128 B: no cross-image line bounce)
#define NB2 8192               // fine value buckets over [0.5,1)
#define HPAD 8200              // per-image hist/dp stride (u32)
#define BAND 4096              // gather band cap (actual band ~62 buckets)

__device__ __forceinline__ float max3(float a, float b, float c) {
    float r;
    asm("v_max3_f32 %0, %1, %2, %3" : "=v"(r) : "v"(a), "v"(b), "v"(c));
    return r;
}
#define MAX5R(A, j) max3(max3(A[j], A[(j)+1], A[(j)+2]), A[(j)+3], A[(j)+4])
#define OR5(A, j) (A[j] | A[(j)+1] | A[(j)+2] | A[(j)+3] | A[(j)+4])

__device__ __forceinline__ u32 bkt(u32 vb) {
    if (vb < 0x3F000000u) return 0u;
    u32 b = ((vb - 0x3F000000u) >> 10) + 1u;
    return b > NB2 ? NB2 : b;
}

__device__ __forceinline__ u64 xdilate(u64 m) {
    return m | (m << 1) | (m >> 1) | (m << 2) | (m >> 2);
}

__device__ __forceinline__ float xmax5(float v) {
    float u1 = __shfl_up(v, 1), d1 = __shfl_down(v, 1);
    float u2 = __shfl_up(v, 2), d2 = __shfl_down(v, 2);
    return max3(max3(v, u1, d1), u2, d2);
}

// mask-bit set -> 0 else v : single v_cndmask on the SGPR-pair ballot
__device__ __forceinline__ float selz(u64 m, float v) {
    float r;
    asm("v_cndmask_b32 %0, %1, 0, %2" : "=v"(r) : "v"(v), "s"(m));
    return r;
}
__device__ __forceinline__ float selnz(u64 m, float v) {
    float r;
    asm("v_cndmask_b32 %0, 0, %1, %2" : "=v"(r) : "v"(v), "s"(m));
    return r;
}

// ---------------- streaming register-pipeline NMS (r16: slab flush, no atomics) ----------------

__global__ __launch_bounds__(256, 4) void k_nms(const float* __restrict__ S_,
                                                u64* __restrict__ cand,
                                                u32* __restrict__ bcnt,
                                                u32* __restrict__ hist) {
    __shared__ u64 lbuf[4][LBUFW];

    int lane = threadIdx.x & 63;
    int wslot = threadIdx.x >> 6;
    int sx = blockIdx.x * 4 + wslot;
    int sy = blockIdx.y;
    int img = blockIdx.z;
    int bid = blockIdx.x + 6 * blockIdx.y;          // 0..191

    // zero this block's disjoint slice of the fine histogram
    {
        u32 base = (u32)bid * 43u;
        u32* gh = hist + (u32)img * HPAD;
        int t0 = threadIdx.x;
        if (t0 < 43 && base + t0 < HPAD) gh[base + t0] = 0;
    }

    int gx0 = sx * 44 - 10;
    int gy0 = sy * 32;
    int gx = gx0 + lane;
    bool lxok = (unsigned)gx < (unsigned)W;
    u64 lanebit = 1ull << lane;
    const float* Sb = S_ + ((size_t)img << 20);

    u64 validx = __ballot(lxok);
    u64 emask = __ballot(lane >= 10 && lane <= 53 && gx >= 2 && gx <= W - 3);

    float S[14], R0[8], R1[8], R2[8], nxt[4];
    u64 M0[8], M1[8], SP1[6], SP2[6];
#pragma unroll
    for (int k = 0; k < 14; ++k) S[k] = -1.0f;
#pragma unroll
    for (int k = 0; k < 8; ++k) { R0[k] = -1e30f; R1[k] = -1e30f; R2[k] = -1e30f; M0[k] = 0; M1[k] = 0; }
#pragma unroll
    for (int k = 0; k < 6; ++k) { SP1[k] = 0; SP2[k] = 0; }

    u32 wbase = 0;
    int y0 = gy0 - 10;

#pragma unroll
    for (int j = 0; j < 4; ++j) {
        int gy = y0 + j;
        nxt[j] = ((unsigned)gy < (unsigned)H && lxok) ? Sb[(gy << 10) + gx] : -1.0f;
    }

    for (int cy = 0; cy < 13; ++cy, y0 += 4) {
#pragma unroll
        for (int j = 0; j < 4; ++j) S[10 + j] = nxt[j];
        if (cy < 12) {
#pragma unroll
            for (int j = 0; j < 4; ++j) {
                int gy = y0 + 4 + j;
                nxt[j] = ((unsigned)gy < (unsigned)H && lxok) ? Sb[(gy << 10) + gx] : -1.0f;
            }
        }
#pragma unroll
        for (int j = 0; j < 4; ++j) {
            R0[4 + j] = xmax5(S[10 + j]);
            float c0 = MAX5R(R0, j);
            u64 m0 = __ballot(S[j + 8] == c0) & validx;
            M0[4 + j] = m0;

            u64 sp1 = xdilate(OR5(M0, j));
            SP1[2 + j] = sp1;

            float ss1 = selz(sp1, S[j + 6]);
            R1[4 + j] = xmax5(ss1);
            float c1 = MAX5R(R1, j);
            float ss1b = selz(SP1[j], S[j + 4]);
            u64 new1 = __ballot(ss1b == c1) & validx;
            u64 m1 = M0[j] | (new1 & ~SP1[j]);
            M1[4 + j] = m1;

            u64 sp2 = xdilate(OR5(M1, j));
            SP2[2 + j] = sp2;

            float ss2 = selz(sp2, S[j + 2]);
            R2[4 + j] = xmax5(ss2);

            if (cy >= 5) {
                float c2 = MAX5R(R2, j);
                float ss2b = selz(SP2[j], S[j]);
                u64 new2 = __ballot(ss2b == c2) & validx;
                u64 m2 = M1[j] | (new2 & ~SP2[j]);
                int gy_out = y0 + j - 10;
                if (gy_out >= 2 && gy_out <= H - 3) {
                    float val = selnz(m2, S[j]);
                    u64 bm = __ballot(val > 0.0f) & emask;
                    if (bm) {
                        u32 cw = (u32)__popcll(bm);
                        u32 prefix = (u32)__popcll(bm & (lanebit - 1ull));
                        if ((bm & lanebit) && (wbase + prefix) < LBUFW) {
                            u64 key = (((u64)__float_as_uint(val)) << 32) |
                                      (u32)(~(u32)((gy_out << 10) + gx));
                            lbuf[wslot][wbase + prefix] = key;
                        }
                        wbase += cw;
                    }
                }
            }
        }
#pragma unroll
        for (int k = 0; k < 10; ++k) S[k] = S[k + 4];
#pragma unroll
        for (int k = 0; k < 4; ++k) {
            R0[k] = R0[k + 4]; R1[k] = R1[k + 4]; R2[k] = R2[k + 4];
            M0[k] = M0[k + 4]; M1[k] = M1[k + 4];
        }
#pragma unroll
        for (int k = 0; k < 2; ++k) { SP1[k] = SP1[k + 4]; SP2[k] = SP2[k + 4]; }
    }

    // slab flush: fixed per-wave slot, no global atomics
    u32 total = wbase > LBUFW ? LBUFW : wbase;
    int slab = bid * 4 + wslot;                     // 0..767
    u64* dst = cand + ((size_t)img << 18) + (size_t)slab * LBUFW;
    for (u32 i = lane; i < total; i += 64)
        dst[i] = lbuf[wslot][i];
    if (lane == 0) bcnt[img * NSLAB + slab] = total;
}

// ---------------- fine histogram: 16 blocks/image, WAVE-grain slab reads ----------------

__global__ __launch_bounds__(256) void k_hist(const u64* __restrict__ cand,
                                              const u32* __restrict__ bcnt,
                                              u32* __restrict__ hist) {
    __shared__ u32 h[NB2 + 1];          // 32.8 KB
    int img = blockIdx.y;
    int t = threadIdx.x;
    int lane = t & 63;
    int wv = blockIdx.x * 4 + (t >> 6);   // 0..63 waves per image
    for (int i = t; i <= NB2; i += 256) h[i] = 0;
    __syncthreads();
    const u64* c = cand + ((size_t)img << 18);
#pragma unroll
    for (int s = 0; s < SPW; ++s) {
        int slab = wv * SPW + s;
        u32 n = bcnt[img * NSLAB + slab];
        if (n > LBUFW) n = LBUFW;
        const u64* cs = c + (size_t)slab * LBUFW;
        for (u32 i = lane; i < n; i += 64)
            atomicAdd(&h[bkt((u32)(cs[i] >> 32))], 1u);
    }
    __syncthreads();
    u32* gh = hist + (u32)img * HPAD;
    for (int i = t; i <= NB2; i += 256) {
        u32 v = h[i];
        if (v) atomicAdd(&gh[i], v);
    }
}

// ---- descending prefix over all buckets -> dparr (+ mutable dpcnt), Bstar, gtot (r13) ----

__global__ __launch_bounds__(1024) void k_scan(const u32* __restrict__ hist,
                                               u32* __restrict__ dparr,
                                               u32* __restrict__ dpcnt,
                                               u32* __restrict__ Bsr,
                                               u32* __restrict__ gtot) {
    __shared__ u32 wpart[16], woff[16];
    __shared__ u32 sBs, sGc;
    int img = blockIdx.x, t = threadIdx.x;
    int lane = t & 63, wid = t >> 6;
    const u32* h = hist + (u32)img * HPAD;
    int hi = NB2 - 8 * t;              // owns buckets hi..hi-7 (covers 8192..1)
    u32 loc[8];
    u32 psum = 0;
#pragma unroll
    for (int i = 0; i < 8; ++i) { loc[i] = h[hi - i]; psum += loc[i]; }
    u32 incl = psum;
#pragma unroll
    for (int d = 1; d < 64; d <<= 1) {
        u32 x = (u32)__shfl_up((int)incl, d);
        if (lane >= d) incl += x;
    }
    if (lane == 63) wpart[wid] = incl;
    if (t == 0) { sBs = 0; sGc = 0; }
    __syncthreads();
    if (t == 0) { u32 a = 0; for (int w2 = 0; w2 < 16; ++w2) { woff[w2] = a; a += wpart[w2]; } }
    __syncthreads();
    u32 total1 = woff[15] + wpart[15];
    u32 excl = incl - psum + woff[wid];     // keys in buckets > hi

    u32* dpi = dparr + (u32)img * HPAD;
    u32* dci = dpcnt + (u32)img * HPAD;
    u32 dpv = excl;
#pragma unroll
    for (int i = 0; i < 8; ++i) {
        dpi[hi - i] = dpv;
        dci[hi - i] = dpv;
        dpv += loc[i];
    }
    if (t == 1023) { dpi[0] = dpv; dci[0] = dpv; }    // dpv == total1
    if (excl < TOPK && excl + psum >= TOPK) {
        u32 cum = excl;
#pragma unroll
        for (int i = 0; i < 8; ++i) {
            cum += loc[i];
            if (cum >= TOPK) { sBs = (u32)(hi - i); sGc = cum; break; }
        }
    }
    __syncthreads();
    if (t == 0) {
        u32 bs = sBs, gc = sGc;
        if (total1 < TOPK) { bs = 0; gc = total1 + h[0]; }
        Bsr[img * CSTR] = bs;
        gtot[img * CSTR] = gc > GCAP ? GCAP : gc;
    }
}

// ---- gather: WAVE-grain slab reads, two-level counting-sort scatter ----

__global__ __launch_bounds__(256) void k_gather(const u64* __restrict__ cand,
                                                const u32* __restrict__ bcnt,
                                                const u32* __restrict__ Bsr,
                                                u32* __restrict__ dpcnt,
                                                u64* __restrict__ gath) {
    __shared__ u32 hb[BAND];   // counts, then consumed offsets
    __shared__ u32 ho[BAND];   // global bases
    int img = blockIdx.y, t = threadIdx.x;
    int lane = t & 63;
    int wv = blockIdx.x * 4 + (t >> 6);
    for (int i = t; i < BAND; i += 256) hb[i] = 0;
    __syncthreads();
    u32 Bs = Bsr[img * CSTR];
    const u64* c = cand + ((size_t)img << 18);
    u32* dci = dpcnt + (u32)img * HPAD;

#pragma unroll
    for (int s = 0; s < SPW; ++s) {
        int slab = wv * SPW + s;
        u32 n = bcnt[img * NSLAB + slab];
        if (n > LBUFW) n = LBUFW;
        const u64* cs = c + (size_t)slab * LBUFW;
        for (u32 i = lane; i < n; i += 64) {
            u32 b = bkt((u32)(cs[i] >> 32));
            if (b >= Bs) {
                u32 idx = b - Bs;
                if (idx < BAND) atomicAdd(&hb[idx], 1u);
            }
        }
    }
    __syncthreads();
    for (int i = t; i < BAND; i += 256) {
        u32 cv = hb[i];
        if (cv) { ho[i] = atomicAdd(&dci[Bs + i], cv); hb[i] = 0; }
    }
    __syncthreads();
    u64* g = gath + ((size_t)img << 13);
#pragma unroll
    for (int s = 0; s < SPW; ++s) {
        int slab = wv * SPW + s;
        u32 n = bcnt[img * NSLAB + slab];
        if (n > LBUFW) n = LBUFW;
        const u64* cs = c + (size_t)slab * LBUFW;
        for (u32 i = lane; i < n; i += 64) {
            u64 key = cs[i];
            u32 b = bkt((u32)(key >> 32));
            if (b < Bs) continue;
            u32 idx = b - Bs;
            u32 pos;
            if (idx < BAND) pos = ho[idx] + atomicAdd(&hb[idx], 1u);
            else pos = atomicAdd(&dci[b], 1u);     // never on this data
            if (pos < GCAP) g[pos] = key;
        }
    }
}

// ---- fused: exact rank (bucket-segment scan) + softmax patch + dispersity + bilinear ----

__global__ __launch_bounds__(256) void k_rankfinal(const u64* __restrict__ gath,
                                                   const u32* __restrict__ gtot,
                                                   const u32* __restrict__ dparr,
                                                   const float* __restrict__ S,
                                                   float* __restrict__ out) {
    int img = blockIdx.y;
    u32 n = gtot[img * CSTR];
    if (n > GCAP) n = GCAP;
    u32 i = blockIdx.x * 256 + threadIdx.x;
    if (i >= n) return;
    const u64* g = gath + ((size_t)img << 13);
    u64 key = g[i];
    u32 b = bkt((u32)(key >> 32));
    const u32* dpi = dparr + (u32)img * HPAD;
    u32 lo = dpi[b];
    u32 hiE = (b >= 1) ? dpi[b - 1] : n;
    if (hiE > n) hiE = n;
    u32 r = lo;
    for (u32 j = lo; j < hiE; ++j) r += (g[j] > key);
    if (r >= TOPK) return;

    u32 rem = ~(u32)(key & 0xFFFFFFFFull);
    int row = (int)(rem >> 10);
    int col = (int)(rem & (W - 1));
    const float* Sb = S + ((size_t)img << 20);

    float p[25];
    float mx = -1e30f;
#pragma unroll
    for (int a2 = 0; a2 < 5; ++a2) {
        int y = row + a2 - 2;
#pragma unroll
        for (int c2 = 0; c2 < 5; ++c2) {
            int x = col + c2 - 2;
            float v = (y >= 0 && y < H && x >= 0 && x < W) ? Sb[(y << 10) + x] : 0.0f;
            p[a2 * 5 + c2] = v;
            mx = fmaxf(mx, v);
        }
    }
    float sum = 0.0f, sx = 0.0f, sy = 0.0f;
#pragma unroll
    for (int a2 = 0; a2 < 5; ++a2) {
#pragma unroll
        for (int c2 = 0; c2 < 5; ++c2) {
            float e = expf((p[a2 * 5 + c2] - mx) / 0.1f);
            p[a2 * 5 + c2] = e;
            sum += e;
            sx += e * (float)(c2 - 2);
            sy += e * (float)(a2 - 2);
        }
    }
    float rx = sx / sum, ry = sy / sum;
    float sd = 0.0f;
#pragma unroll
    for (int a2 = 0; a2 < 5; ++a2) {
#pragma unroll
        for (int c2 = 0; c2 < 5; ++c2) {
            float dxx = ((float)(c2 - 2) - rx) * 0.5f;
            float dyy = ((float)(a2 - 2) - ry) * 0.5f;
            sd += p[a2 * 5 + c2] * (dxx * dxx + dyy * dyy);
        }
    }
    float disp = sd / sum;
    float kx = ((float)col + rx) / (float)(W - 1) * 2.0f - 1.0f;
    float ky = ((float)row + ry) / (float)(H - 1) * 2.0f - 1.0f;

    float px = (kx + 1.0f) * 0.5f * (float)(W - 1);
    float py = (ky + 1.0f) * 0.5f * (float)(H - 1);
    float x0 = floorf(px), y0 = floorf(py);
    float wx1 = px - x0, wx0 = 1.0f - wx1;
    float wy1 = py - y0, wy0 = 1.0f - wy1;

    float gg[4];
    float xs[4] = {x0, x0 + 1.0f, x0, x0 + 1.0f};
    float ys[4] = {y0, y0, y0 + 1.0f, y0 + 1.0f};
#pragma unroll
    for (int q = 0; q < 4; ++q) {
        int xi = (int)xs[q]; xi = xi < 0 ? 0 : (xi > W - 1 ? W - 1 : xi);
        int yi = (int)ys[q]; yi = yi < 0 ? 0 : (yi > H - 1 ? H - 1 : yi);
        bool valid = (xs[q] >= 0.0f) && (xs[q] <= (float)(W - 1)) &&
                     (ys[q] >= 0.0f) && (ys[q] <= (float)(H - 1));
        gg[q] = valid ? Sb[(yi << 10) + xi] : 0.0f;
    }
    float score = wy0 * wx0 * gg[0] + wy0 * wx1 * gg[1] + wy1 * wx0 * gg[2] + wy1 * wx1 * gg[3];

    u32 slot = ((u32)img << 12) + r;
    out[(size_t)slot * 2]     = kx;
    out[(size_t)slot * 2 + 1] = ky;
    out[B * TOPK * 2 + slot]            = disp;
    out[B * TOPK * 2 + B * TOPK + slot] = score;
}

// ---------------- launch ----------------

extern "C" void kernel_launch(void* const* d_in, const int* in_sizes, int n_in,
                              void* d_out, int out_size, void* d_ws, size_t ws_size,
                              hipStream_t stream) {
    const float* S = (const float*)d_in[0];
    float* out = (float*)d_out;

    char* w = (char*)d_ws;
    u64* cand = (u64*)w;        w += (size_t)B * (1 << 18) * 8;   // slabbed: 768 x 320 per image
    u64* gath = (u64*)w;        w += (size_t)B * GCAP * 8;
    u32* hist = (u32*)w;        w += (size_t)B * HPAD * 4;
    u32* dparr = (u32*)w;       w += (size_t)B * HPAD * 4;
    u32* dpcnt = (u32*)w;       w += (size_t)B * HPAD * 4;
    u32* bcnt = (u32*)w;        w += (size_t)B * NSLAB * 4;
    u32* Bsr = (u32*)w;         w += B * CSTR * 4;
    u32* gtot = (u32*)w;        w += B * CSTR * 4;

    // no memset: hist zeroed inside k_nms (disjoint slices); bcnt fully written
    // by k_nms; dparr/dpcnt/Bsr/gtot fully written by k_scan.

    k_nms<<<dim3(6, 32, B), 256, 0, stream>>>(S, cand, bcnt, hist);
    k_hist<<<dim3(16, B), 256, 0, stream>>>(cand, bcnt, hist);
    k_scan<<<B, 1024, 0, stream>>>(hist, dparr, dpcnt, Bsr, gtot);
    k_gather<<<dim3(16, B), 256, 0, stream>>>(cand, bcnt, Bsr, dpcnt, gath);
    k_rankfinal<<<dim3(32, B), 256, 0, stream>>>(gath, gtot, dparr, S, out);
}